// Round 4
// baseline (76.221 us; speedup 1.0000x reference)
//
#include <hip/hip_runtime.h>
#include <hip/hip_bf16.h>

// Problem constants (Atten_tit): B=16, T=256, K=256, H=512, A=49
#define B_ 16
#define T_ 256
#define K_ 256
#define H_ 512
#define A_ 49
#define APAD 64

typedef __attribute__((ext_vector_type(8))) short short8;   // bf16x8
typedef __attribute__((ext_vector_type(4))) float f32x4;

__device__ __forceinline__ ushort f2bf(float f) {
    uint u = __builtin_bit_cast(uint, f);
    u += 0x7FFF + ((u >> 16) & 1);   // RNE
    return (ushort)(u >> 16);
}

__device__ __forceinline__ float tanh_fast(float x) {
    // tanh(x) = 1 - 2/(e^{2x}+1)
    float xc = fminf(fmaxf(x, -15.f), 15.f);
    float e = __expf(2.f * xc);
    float r = __builtin_amdgcn_rcpf(e + 1.f);
    return 1.f - 2.f * r;
}

// ---------------------------------------------------------------------------
// kA: blocks [0,512): projection GEMM  C(8192x64) = X(8192x512)·W^T, M-tile 16.
//     rows 0..4095 (des) -> cvT (B,64,K) f32 transposed; rows 4096.. -> cg (B*T,64).
//     blocks [512,2560): transpose des (B,K,H) f32 -> desT (B,H,K) bf16, 32x32 tiles.
__global__ __launch_bounds__(256) void kA(const float* __restrict__ des,
                                          const float* __restrict__ title,
                                          const float* __restrict__ Wv,
                                          const float* __restrict__ Wg,
                                          float* __restrict__ cvT,
                                          float* __restrict__ cg,
                                          ushort* __restrict__ desT)
{
    __shared__ float Xs[32][17];
    __shared__ float Ws[32][68];
    __shared__ float Tls[32][33];

    int tid = threadIdx.x;

    if (blockIdx.x >= 512) {
        // ---- transpose branch ----
        int tb = blockIdx.x - 512;            // 0..2047 = b(16) x kt(8) x ht(16)
        int b = tb >> 7, rem = tb & 127;
        int k0 = (rem >> 4) * 32, h0 = (rem & 15) * 32;
        int kk = tid >> 3, c4 = (tid & 7) * 4;
        float4 v = *(const float4*)(des + ((size_t)(b * K_ + k0 + kk) * H_) + h0 + c4);
        Tls[kk][c4 + 0] = v.x; Tls[kk][c4 + 1] = v.y;
        Tls[kk][c4 + 2] = v.z; Tls[kk][c4 + 3] = v.w;
        __syncthreads();
        int hh = tid >> 3;
        ushort4 o;
        o.x = f2bf(Tls[c4 + 0][hh]);
        o.y = f2bf(Tls[c4 + 1][hh]);
        o.z = f2bf(Tls[c4 + 2][hh]);
        o.w = f2bf(Tls[c4 + 3][hh]);
        *(ushort4*)(desT + ((size_t)(b * H_ + h0 + hh) * K_) + k0 + c4) = o;
        return;
    }

    // ---- projection branch ----
    int bid = blockIdx.x;
    bool isCv = bid < 256;
    int r0 = (isCv ? bid : bid - 256) * 16;
    const float* X = (isCv ? des : title) + (size_t)r0 * H_;
    const float* W = isCv ? Wv : Wg;

    int tx = tid & 15, ty = tid >> 4;        // tx: a-quad, ty: row
    float acc[4] = {};

    int xrow = tid >> 4, xk = (tid & 15) * 2;   // X tile 16x32 / 256 thr = 2
    int wa = tid >> 2,  wk = (tid & 3) * 8;     // W tile 64x32 / 256 thr = 8

    for (int k0 = 0; k0 < H_; k0 += 32) {
        {
            float2 v = *(const float2*)(X + (size_t)xrow * H_ + k0 + xk);
            Xs[xk][xrow] = v.x; Xs[xk + 1][xrow] = v.y;
        }
        {
            float4 v0 = make_float4(0.f,0.f,0.f,0.f), v1 = v0;
            if (wa < A_) {
                v0 = *(const float4*)(W + (size_t)wa * H_ + k0 + wk);
                v1 = *(const float4*)(W + (size_t)wa * H_ + k0 + wk + 4);
            }
            Ws[wk + 0][wa] = v0.x; Ws[wk + 1][wa] = v0.y;
            Ws[wk + 2][wa] = v0.z; Ws[wk + 3][wa] = v0.w;
            Ws[wk + 4][wa] = v1.x; Ws[wk + 5][wa] = v1.y;
            Ws[wk + 6][wa] = v1.z; Ws[wk + 7][wa] = v1.w;
        }
        __syncthreads();
        #pragma unroll
        for (int kk = 0; kk < 32; ++kk) {
            float a0 = Xs[kk][ty];
            float4 w4 = *(const float4*)(&Ws[kk][tx * 4]);
            acc[0] += a0 * w4.x; acc[1] += a0 * w4.y;
            acc[2] += a0 * w4.z; acc[3] += a0 * w4.w;
        }
        __syncthreads();
    }

    if (isCv) {
        int b = r0 >> 8, kb = r0 & 255;
        #pragma unroll
        for (int j = 0; j < 4; ++j) {
            int a = tx * 4 + j;
            cvT[((size_t)(b * APAD + a)) * K_ + kb + ty] = acc[j];
        }
    } else {
        int r = r0 + ty;   // title-local row index (b*T + t); r0 already rebased
        *(float4*)(cg + (size_t)r * APAD + tx * 4) =
            make_float4(acc[0], acc[1], acc[2], acc[3]);
    }
}

// ---------------------------------------------------------------------------
// kZ: fused z + softmax + PV. One block per (b, 16-row t-tile). 256 threads.
// Thread k: z[t] = sum_a tanh(cvT[b,a,k] + cg[b,t,a]) * Wh[a]  (16 t's in regs)
// Block softmax over k per t; alpha -> global f32 + LDS bf16; then PV MFMA:
// c_hat(16t x 512h) = alpha(16 x 256) * des(256 x 512) via desT bf16.
__global__ __launch_bounds__(256) void kZ(const float* __restrict__ cvT,
                                          const float* __restrict__ cg,
                                          const float* __restrict__ Wh,
                                          const ushort* __restrict__ desT,
                                          float* __restrict__ alpha,
                                          float* __restrict__ chat)
{
    __shared__ float  sCg[16][APAD];       // 4 KB
    __shared__ float  sWh[APAD];
    __shared__ float  sRedM[16][4];
    __shared__ float  sRedS[16][4];
    __shared__ ushort sA[16][K_ + 8];      // alpha bf16, padded stride 528B

    int bid = blockIdx.x;
    int b  = bid >> 4;
    int t0 = (bid & 15) << 4;
    int tid = threadIdx.x;
    int k = tid;

    {
        int row = tid >> 4, c = (tid & 15) * 4;
        *(float4*)(&sCg[row][c]) =
            *(const float4*)(cg + (size_t)(b * T_ + t0 + row) * APAD + c);
    }
    if (tid < APAD) sWh[tid] = (tid < A_) ? Wh[tid] : 0.f;
    __syncthreads();

    // ---- z phase: 16 accumulators, cv value loaded once per a ----
    float z[16];
    #pragma unroll
    for (int t = 0; t < 16; ++t) z[t] = 0.f;

    const float* cvp = cvT + (size_t)b * APAD * K_ + k;
    for (int a = 0; a < A_; ++a) {
        float xa = cvp[(size_t)a * K_];
        float wh = sWh[a];
        #pragma unroll
        for (int t = 0; t < 16; ++t)
            z[t] += tanh_fast(xa + sCg[t][a]) * wh;
    }

    // ---- softmax over k (256 threads = 4 waves) ----
    int wid = tid >> 6, lane = tid & 63;
    #pragma unroll
    for (int t = 0; t < 16; ++t) {
        float m = z[t];
        #pragma unroll
        for (int off = 32; off > 0; off >>= 1) m = fmaxf(m, __shfl_xor(m, off));
        if (lane == 0) sRedM[t][wid] = m;
    }
    __syncthreads();
    #pragma unroll
    for (int t = 0; t < 16; ++t) {
        float m = fmaxf(fmaxf(sRedM[t][0], sRedM[t][1]),
                        fmaxf(sRedM[t][2], sRedM[t][3]));
        z[t] = __expf(z[t] - m);
    }
    #pragma unroll
    for (int t = 0; t < 16; ++t) {
        float s = z[t];
        #pragma unroll
        for (int off = 32; off > 0; off >>= 1) s += __shfl_xor(s, off);
        if (lane == 0) sRedS[t][wid] = s;
    }
    __syncthreads();
    #pragma unroll
    for (int t = 0; t < 16; ++t) {
        float s = sRedS[t][0] + sRedS[t][1] + sRedS[t][2] + sRedS[t][3];
        float rs = __builtin_amdgcn_rcpf(s);
        rs = rs * (2.f - s * rs);            // Newton step
        float al = z[t] * rs;
        alpha[(size_t)(b * T_ + t0 + t) * K_ + k] = al;
        sA[t][k] = f2bf(al);
    }
    __syncthreads();

    // ---- PV phase: 4 waves, wave w -> h-panel [w*128, w*128+128) ----
    int w  = tid >> 6;
    int lr = lane & 15, lc = lane >> 4;
    int h0 = w * 128;

    const ushort* Bp = desT + ((size_t)(b * H_ + h0 + lr)) * K_ + lc * 8;

    f32x4 accs[8] = {};
    #pragma unroll
    for (int kb = 0; kb < K_; kb += 32) {
        short8 a8 = *(const short8*)(&sA[lr][kb + lc * 8]);
        #pragma unroll
        for (int j = 0; j < 8; ++j) {
            short8 b8 = *(const short8*)(Bp + (size_t)(j * 16) * K_ + kb);
            accs[j] = __builtin_amdgcn_mfma_f32_16x16x32_bf16(a8, b8, accs[j], 0, 0, 0);
        }
    }

    #pragma unroll
    for (int j = 0; j < 8; ++j) {
        #pragma unroll
        for (int r = 0; r < 4; ++r) {
            int row = t0 + lc * 4 + r;
            int col = h0 + j * 16 + lr;
            chat[((size_t)(b * T_ + row)) * H_ + col] = accs[j][r];
        }
    }
}

// ---------------------------------------------------------------------------
extern "C" void kernel_launch(void* const* d_in, const int* in_sizes, int n_in,
                              void* d_out, int out_size, void* d_ws, size_t ws_size,
                              hipStream_t stream) {
    const float* des   = (const float*)d_in[0];
    const float* title = (const float*)d_in[1];
    const float* Wv    = (const float*)d_in[2];
    const float* Wg    = (const float*)d_in[3];
    const float* Wh    = (const float*)d_in[4];

    float* chat  = (float*)d_out;                            // (B,T,H)
    float* alpha = (float*)d_out + (size_t)B_ * T_ * H_;     // (B,T,K)

    char* ws = (char*)d_ws;
    float*  cvT  = (float*)ws;                               // (B,64,K) f32: 1 MB
    float*  cg   = cvT + (size_t)B_ * APAD * K_;             // (B*T,64) f32: 1 MB
    ushort* desT = (ushort*)(cg + (size_t)B_ * T_ * APAD);   // (B,H,K) bf16: 4 MB

    hipLaunchKernelGGL(kA, dim3(2560), dim3(256), 0, stream,
                       des, title, Wv, Wg, cvT, cg, desT);
    hipLaunchKernelGGL(kZ, dim3(B_ * (T_ / 16)), dim3(256), 0, stream,
                       cvT, cg, Wh, desT, alpha, chat);
}

// Round 5
// 73.167 us; speedup vs baseline: 1.0417x; 1.0417x over previous
//
#include <hip/hip_runtime.h>
#include <hip/hip_bf16.h>

// Problem constants (Atten_tit): B=16, T=256, K=256, H=512, A=49
#define B_ 16
#define T_ 256
#define K_ 256
#define H_ 512
#define A_ 49
#define APAD 64

typedef __attribute__((ext_vector_type(8))) short short8;   // bf16x8
typedef __attribute__((ext_vector_type(4))) float f32x4;

__device__ __forceinline__ ushort f2bf(float f) {
    uint u = __builtin_bit_cast(uint, f);
    u += 0x7FFF + ((u >> 16) & 1);   // RNE
    return (ushort)(u >> 16);
}

// split f32 -> bf16 hi + bf16 lo (residual). hi+lo carries ~17 mantissa bits.
__device__ __forceinline__ void cvt_hilo(float4 v0, float4 v1, short8& hi, short8& lo) {
    float v[8] = {v0.x, v0.y, v0.z, v0.w, v1.x, v1.y, v1.z, v1.w};
    #pragma unroll
    for (int i = 0; i < 8; ++i) {
        ushort h = f2bf(v[i]);
        float hf = __builtin_bit_cast(float, (uint)h << 16);
        hi[i] = (short)h;
        lo[i] = (short)f2bf(v[i] - hf);
    }
}

__device__ __forceinline__ float tanh_fast(float x) {
    // tanh(x) = 1 - 2/(e^{2x}+1); exp saturation gives correct +-1 at extremes.
    float e = __expf(2.f * x);
    return 1.f - 2.f * __builtin_amdgcn_rcpf(e + 1.f);
}

// ---------------------------------------------------------------------------
// kAP: blocks [0,2048): transpose des (B,K,H) f32 -> desT (B,H,K) bf16 (32x32 tiles)
//      blocks [2048,2176): projection via split-bf16 MFMA, one 16-row tile per wave.
//        des tiles  (0..255):  C = W(a) x des-rows -> cvT (B,64,K), a-major
//        title tiles(256..511): C = title-rows x W(a) -> cg (B*T,64), a-minor
__global__ __launch_bounds__(256) void kAP(const float* __restrict__ des,
                                           const float* __restrict__ title,
                                           const float* __restrict__ Wv,
                                           const float* __restrict__ Wg,
                                           float* __restrict__ cvT,
                                           float* __restrict__ cg,
                                           ushort* __restrict__ desT)
{
    __shared__ float Tls[32][33];
    int tid = threadIdx.x;

    if (blockIdx.x < 2048) {
        // ---- transpose branch ----
        int tb = blockIdx.x;                  // b(16) x kt(8) x ht(16)
        int b = tb >> 7, rem = tb & 127;
        int k0 = (rem >> 4) * 32, h0 = (rem & 15) * 32;
        int kk = tid >> 3, c4 = (tid & 7) * 4;
        float4 v = *(const float4*)(des + ((size_t)(b * K_ + k0 + kk) * H_) + h0 + c4);
        Tls[kk][c4 + 0] = v.x; Tls[kk][c4 + 1] = v.y;
        Tls[kk][c4 + 2] = v.z; Tls[kk][c4 + 3] = v.w;
        __syncthreads();
        int hh = tid >> 3;
        ushort4 o;
        o.x = f2bf(Tls[c4 + 0][hh]);
        o.y = f2bf(Tls[c4 + 1][hh]);
        o.z = f2bf(Tls[c4 + 2][hh]);
        o.w = f2bf(Tls[c4 + 3][hh]);
        *(ushort4*)(desT + ((size_t)(b * H_ + h0 + hh) * K_) + k0 + c4) = o;
        return;
    }

    // ---- projection branch: one 16-row tile per wave ----
    int wv = tid >> 6, lane = tid & 63;
    int tile = (blockIdx.x - 2048) * 4 + wv;      // 0..511
    bool isDes = tile < 256;
    int lr = lane & 15, lc = lane >> 4;

    const float* X  = isDes ? (des + (size_t)tile * 16 * H_)
                            : (title + (size_t)(tile - 256) * 16 * H_);
    const float* Wm = isDes ? Wv : Wg;

    f32x4 acc[4] = {};

    for (int k0 = 0; k0 < H_; k0 += 32) {
        // X fragment: row lr, k = k0 + lc*8 .. +8
        const float* xp = X + (size_t)lr * H_ + k0 + lc * 8;
        float4 xv0 = *(const float4*)xp;
        float4 xv1 = *(const float4*)(xp + 4);
        short8 xhi, xlo;
        cvt_hilo(xv0, xv1, xhi, xlo);

        #pragma unroll
        for (int g = 0; g < 4; ++g) {
            int wrow = g * 16 + lr;
            if (wrow > A_ - 1) wrow = A_ - 1;     // clamp: avoid OOB, cols >=49 unused
            const float* wp = Wm + (size_t)wrow * H_ + k0 + lc * 8;
            float4 wv0 = *(const float4*)wp;
            float4 wv1 = *(const float4*)(wp + 4);
            short8 whi, wlo;
            cvt_hilo(wv0, wv1, whi, wlo);
            if (isDes) {   // A = W (rows=a), B = X (cols=k-row)
                acc[g] = __builtin_amdgcn_mfma_f32_16x16x32_bf16(whi, xhi, acc[g], 0, 0, 0);
                acc[g] = __builtin_amdgcn_mfma_f32_16x16x32_bf16(whi, xlo, acc[g], 0, 0, 0);
                acc[g] = __builtin_amdgcn_mfma_f32_16x16x32_bf16(wlo, xhi, acc[g], 0, 0, 0);
            } else {       // A = X (rows=t), B = W (cols=a)
                acc[g] = __builtin_amdgcn_mfma_f32_16x16x32_bf16(xhi, whi, acc[g], 0, 0, 0);
                acc[g] = __builtin_amdgcn_mfma_f32_16x16x32_bf16(xlo, whi, acc[g], 0, 0, 0);
                acc[g] = __builtin_amdgcn_mfma_f32_16x16x32_bf16(xhi, wlo, acc[g], 0, 0, 0);
            }
        }
    }

    if (isDes) {
        int krows = tile * 16;
        int b = krows >> 8, kb = krows & 255;
        #pragma unroll
        for (int g = 0; g < 4; ++g)
            #pragma unroll
            for (int r = 0; r < 4; ++r) {
                int a = g * 16 + lc * 4 + r;       // C row = a
                cvT[((size_t)b * APAD + a) * K_ + kb + lr] = acc[g][r];
            }
    } else {
        int trows = (tile - 256) * 16;             // global title row (b*T + t)
        #pragma unroll
        for (int g = 0; g < 4; ++g)
            #pragma unroll
            for (int r = 0; r < 4; ++r) {
                int row = trows + lc * 4 + r;      // C row = t
                cg[(size_t)row * APAD + g * 16 + lr] = acc[g][r];
            }
    }
}

// ---------------------------------------------------------------------------
// kZ: fused z + softmax + PV. One block per (b, 16-row t-tile). 1024 threads.
// Thread (k = tid&255, tg = tid>>8): z[j] for t = tg*4+j over a<49.
// Softmax over k within each tg-group (4 waves). PV: 16 waves x 32-h panels.
__global__ __launch_bounds__(1024) void kZ(const float* __restrict__ cvT,
                                           const float* __restrict__ cg,
                                           const float* __restrict__ Wh,
                                           const ushort* __restrict__ desT,
                                           float* __restrict__ alpha,
                                           float* __restrict__ chat)
{
    __shared__ float  sCg[16][APAD];       // 4 KB
    __shared__ float  sWh[APAD];
    __shared__ float  sRedM[16][4];
    __shared__ float  sRedS[16][4];
    __shared__ ushort sA[16][K_ + 8];      // alpha bf16, padded

    int bid = blockIdx.x;
    int b  = bid >> 4;
    int t0 = (bid & 15) << 4;
    int tid = threadIdx.x;
    int k  = tid & 255;
    int tg = tid >> 8;                     // 0..3

    if (tid < 256) {
        int row = tid >> 4, c = (tid & 15) * 4;
        *(float4*)(&sCg[row][c]) =
            *(const float4*)(cg + (size_t)(b * T_ + t0 + row) * APAD + c);
    } else if (tid < 256 + APAD) {
        int a = tid - 256;
        sWh[a] = (a < A_) ? Wh[a] : 0.f;
    }
    __syncthreads();

    // ---- z phase: 4 accumulators per thread ----
    float z[4] = {0.f, 0.f, 0.f, 0.f};
    const float* cvp = cvT + (size_t)b * APAD * K_ + k;
    for (int a = 0; a < A_; ++a) {
        float xa = cvp[(size_t)a * K_];
        float wh = sWh[a];
        #pragma unroll
        for (int j = 0; j < 4; ++j)
            z[j] += tanh_fast(xa + sCg[tg * 4 + j][a]) * wh;
    }

    // ---- softmax over k (4 waves per tg group) ----
    int wv = tid >> 6, lane = tid & 63, w3 = wv & 3;
    #pragma unroll
    for (int j = 0; j < 4; ++j) {
        float m = z[j];
        #pragma unroll
        for (int off = 32; off > 0; off >>= 1) m = fmaxf(m, __shfl_xor(m, off));
        if (lane == 0) sRedM[tg * 4 + j][w3] = m;
    }
    __syncthreads();
    #pragma unroll
    for (int j = 0; j < 4; ++j) {
        int t = tg * 4 + j;
        float m = fmaxf(fmaxf(sRedM[t][0], sRedM[t][1]),
                        fmaxf(sRedM[t][2], sRedM[t][3]));
        z[j] = __expf(z[j] - m);
    }
    #pragma unroll
    for (int j = 0; j < 4; ++j) {
        float s = z[j];
        #pragma unroll
        for (int off = 32; off > 0; off >>= 1) s += __shfl_xor(s, off);
        if (lane == 0) sRedS[tg * 4 + j][w3] = s;
    }
    __syncthreads();
    #pragma unroll
    for (int j = 0; j < 4; ++j) {
        int t = tg * 4 + j;
        float s = sRedS[t][0] + sRedS[t][1] + sRedS[t][2] + sRedS[t][3];
        float rs = __builtin_amdgcn_rcpf(s);
        rs = rs * (2.f - s * rs);              // Newton step
        float al = z[j] * rs;
        alpha[(size_t)(b * T_ + t0 + t) * K_ + k] = al;
        sA[t][k] = f2bf(al);
    }
    __syncthreads();

    // ---- PV: 16 waves, wave wv -> h-panel [wv*32, wv*32+32) ----
    int lr = lane & 15, lc = lane >> 4;
    int h0 = wv * 32;
    const ushort* Bp = desT + ((size_t)(b * H_ + h0 + lr)) * K_ + lc * 8;

    f32x4 acc0 = {}, acc1 = {};
    #pragma unroll
    for (int kb = 0; kb < K_; kb += 32) {
        short8 a8 = *(const short8*)(&sA[lr][kb + lc * 8]);
        short8 b0 = *(const short8*)(Bp + kb);
        short8 b1 = *(const short8*)(Bp + (size_t)16 * K_ + kb);
        acc0 = __builtin_amdgcn_mfma_f32_16x16x32_bf16(a8, b0, acc0, 0, 0, 0);
        acc1 = __builtin_amdgcn_mfma_f32_16x16x32_bf16(a8, b1, acc1, 0, 0, 0);
    }

    #pragma unroll
    for (int r = 0; r < 4; ++r) {
        int row = t0 + lc * 4 + r;
        chat[((size_t)(b * T_ + row)) * H_ + h0 + lr]      = acc0[r];
        chat[((size_t)(b * T_ + row)) * H_ + h0 + 16 + lr] = acc1[r];
    }
}

// ---------------------------------------------------------------------------
extern "C" void kernel_launch(void* const* d_in, const int* in_sizes, int n_in,
                              void* d_out, int out_size, void* d_ws, size_t ws_size,
                              hipStream_t stream) {
    const float* des   = (const float*)d_in[0];
    const float* title = (const float*)d_in[1];
    const float* Wv    = (const float*)d_in[2];
    const float* Wg    = (const float*)d_in[3];
    const float* Wh    = (const float*)d_in[4];

    float* chat  = (float*)d_out;                            // (B,T,H)
    float* alpha = (float*)d_out + (size_t)B_ * T_ * H_;     // (B,T,K)

    char* ws = (char*)d_ws;
    float*  cvT  = (float*)ws;                               // (B,64,K) f32: 1 MB
    float*  cg   = cvT + (size_t)B_ * APAD * K_;             // (B*T,64) f32: 1 MB
    ushort* desT = (ushort*)(cg + (size_t)B_ * T_ * APAD);   // (B,H,K) bf16: 4 MB

    hipLaunchKernelGGL(kAP, dim3(2176), dim3(256), 0, stream,
                       des, title, Wv, Wg, cvT, cg, desT);
    hipLaunchKernelGGL(kZ, dim3(B_ * (T_ / 16)), dim3(1024), 0, stream,
                       cvT, cg, Wh, desT, alpha, chat);
}